// Round 9
// baseline (271.813 us; speedup 1.0000x reference)
//
#include <hip/hip_runtime.h>
#include <math.h>

using u16 = unsigned short;
typedef __attribute__((ext_vector_type(8))) short short8;
typedef __attribute__((ext_vector_type(16))) float floatx16;

constexpr int Bc = 32, Nn = 500, Mm = 500, Dd = 256;
constexpr float LOGIT_CLIP = 10.0f;
constexpr float INV_SQRT_D = 1.0f / 16.0f;

__device__ __forceinline__ floatx16 mfma32(short8 a, short8 b, floatx16 c) {
    return __builtin_amdgcn_mfma_f32_32x32x16_bf16(a, b, c, 0, 0, 0);
}

__device__ __forceinline__ floatx16 zero16() {
    floatx16 v = {0.f,0.f,0.f,0.f,0.f,0.f,0.f,0.f,0.f,0.f,0.f,0.f,0.f,0.f,0.f,0.f};
    return v;
}

// split fp32 x into bf16 hi (RTN) + bf16 lo (RTN of residual): x ~= hi + lo
__device__ __forceinline__ void split1(float x, u16& h, u16& l) {
    unsigned u = __float_as_uint(x);
    unsigned rh = (u + 0x7FFFu + ((u >> 16) & 1u)) & 0xFFFF0000u;
    float fh = __uint_as_float(rh);
    float fl = x - fh;
    unsigned ul = __float_as_uint(fl);
    unsigned rl = ul + 0x7FFFu + ((ul >> 16) & 1u);
    h = (u16)(rh >> 16);
    l = (u16)(rl >> 16);
}

__device__ __forceinline__ u16 bf16rtn(float x) {
    unsigned u = __float_as_uint(x);
    return (u16)((u + 0x7FFFu + ((u >> 16) & 1u)) >> 16);
}

__device__ __forceinline__ float fast_tanh(float x) {
    return 1.0f - 2.0f / (__expf(2.0f * x) + 1.0f);
}

__device__ __forceinline__ void split8(const float4& a, const float4& c,
                                       short8& hv, short8& lv) {
    u16 hh, ll;
    split1(a.x, hh, ll); hv[0] = (short)hh; lv[0] = (short)ll;
    split1(a.y, hh, ll); hv[1] = (short)hh; lv[1] = (short)ll;
    split1(a.z, hh, ll); hv[2] = (short)hh; lv[2] = (short)ll;
    split1(a.w, hh, ll); hv[3] = (short)hh; lv[3] = (short)ll;
    split1(c.x, hh, ll); hv[4] = (short)hh; lv[4] = (short)ll;
    split1(c.y, hh, ll); hv[5] = (short)hh; lv[5] = (short)ll;
    split1(c.z, hh, ll); hv[6] = (short)hh; lv[6] = (short)ll;
    split1(c.w, hh, ll); hv[7] = (short)hh; lv[7] = (short)ll;
}

// ===========================================================================
// Packed fragment layouts (u16 units), fragment = [lane(64)][e(8)] = 512 u16:
//   element (row r, col d) lives at lane=((d>>3)&1)<<5 | (r&31), e = d&7.
//   tile stride: 16 dc-chunks x 2 arr(H/L) x 512 = 16384 u16 per 32-row tile.
// PKW [w(4)][dt(8)]  : weights,  w = {Wk,Wv,Wq0,Wq1}, rows = out-dim.
// PKJ [b][mt(16)]    : jobs,   rows m (zero-padded to 512).
// PKB [b][dt(8)][mc(32)][arr(4: ekH,ekL,ekvH,ekvL)][512] : ek/ekv transposed.
// SQ_PK [b][nt(16)][dt(8)][lane(64)][r(16)] fp32 : sigmoid(q), C/D-fragment
//   layout (same (r,lane)->(row,col) map as the MFMA accumulator).
// ===========================================================================

// ---------------------------------------------------------------------------
// K0w_pk: weights fp32 -> packed bf16 hi/lo fragments
// ---------------------------------------------------------------------------
__global__ __launch_bounds__(256) void k0w_pk(const float* __restrict__ s0,
                                              const float* __restrict__ s1,
                                              const float* __restrict__ s2,
                                              const float* __restrict__ s3,
                                              u16* __restrict__ pkw) {
    const float* s = blockIdx.y == 0 ? s0 : blockIdx.y == 1 ? s1 :
                     blockIdx.y == 2 ? s2 : s3;
    const int w = blockIdx.y;
    const int flat = (blockIdx.x * 256 + threadIdx.x) * 8;   // 0..65535
    const int i = flat >> 8, j0 = flat & 255;
    float4 a = *(const float4*)&s[flat];
    float4 c = *(const float4*)&s[flat + 4];
    short8 hv, lv;
    split8(a, c, hv, lv);
    const int dt = i >> 5, i31 = i & 31, dc = j0 >> 4, hp = (j0 >> 3) & 1;
    const size_t off = (size_t)(w * 8 + dt) * 16384 + (size_t)dc * 1024
                     + (size_t)((hp << 5) | i31) * 8;
    *(short8*)&pkw[off] = hv;
    *(short8*)&pkw[off + 512] = lv;
}

// ---------------------------------------------------------------------------
// K12: merged k1 + k2 (independent passes; merged for co-residency).
// Grid (16, 32, 2), 512 thr / 8 waves; blockIdx.z picks role.
// Role 0 (k1): fused jobs-packing + k/v GEMM -> pkj + PKB (round-8 k1).
// Role 1 (k2): sq = sigmoid(q0@Wq0^T + q1@Wq1^T), TWO-PASS staging
//   (q0 pass then q1 pass reusing one 33KB LDS buffer, same accumulator).
// ---------------------------------------------------------------------------
__global__ __launch_bounds__(512) void k12(const float* __restrict__ jobs,
                                           const float* __restrict__ q0,
                                           const float* __restrict__ q1,
                                           const u16* __restrict__ pkw,
                                           u16* __restrict__ pkj,
                                           u16* __restrict__ pkb,
                                           float* __restrict__ sq) {
    __shared__ u16 tq[2][32][264];   // [H|L][row][col(+pad)]
    const int t = threadIdx.x;
    const int lane = t & 63, wv = t >> 6;   // wv 0..7
    const int l31 = lane & 31, h = lane >> 5;
    const int tile = blockIdx.x;            // 0..15
    const int b = blockIdx.y;

    if (blockIdx.z == 0) {
        // ================= role 0: k1 (jobs -> pkj, PKB) =================
        const int mt = tile;
        const int M0 = mt * 32;

        // ---- phase A: stage jobs tile (32 rows x 256 cols fp32) ----
#pragma unroll
        for (int it = 0; it < 2; ++it) {
            const int flat = (it * 512 + t) * 8;    // 0..8191
            const int nl = flat >> 8, j0 = flat & 255;
            const int m = M0 + nl;
            short8 hv = {0,0,0,0,0,0,0,0}, lv = {0,0,0,0,0,0,0,0};
            if (m < Mm) {
                const size_t o = ((size_t)b * Mm + m) * Dd + j0;
                float4 a = *(const float4*)&jobs[o];
                float4 c = *(const float4*)&jobs[o + 4];
                split8(a, c, hv, lv);
            }
            *(short8*)&tq[0][nl][j0] = hv;
            *(short8*)&tq[1][nl][j0] = lv;
        }
        __syncthreads();

        // ---- phase B: pkj tile write (fragment layout, coalesced) ----
        {
            u16* dst = pkj + (size_t)(b * 16 + mt) * 16384;
#pragma unroll
            for (int it = 0; it < 4; ++it) {
                const int u = it * 512 + t;        // 0..2047 short8s
                const int dc = u >> 7;
                const int rem = u & 127;
                const int sel = rem >> 6;
                const int idx = rem & 63;
                const int hp = idx >> 5, r31 = idx & 31;
                short8 v = *(const short8*)&tq[sel][r31][dc * 16 + hp * 8];
                *(short8*)&dst[(size_t)dc * 1024 + sel * 512 + (size_t)idx * 8] = v;
            }
        }

        // ---- phase C: GEMM, wave wv -> dt = wv ----
        const int dt = wv;
        const size_t wk  = (size_t)dt * 16384 + (size_t)lane * 8;         // Wk
        const size_t wvb = (size_t)(8 + dt) * 16384 + (size_t)lane * 8;   // Wv

        floatx16 ak = zero16(), av = zero16();

        short8 buf[3][4];
#define K1L(S, DC) { \
        buf[S][0] = *(const short8*)(pkw + wk  + (size_t)(DC) * 1024); \
        buf[S][1] = *(const short8*)(pkw + wk  + (size_t)(DC) * 1024 + 512); \
        buf[S][2] = *(const short8*)(pkw + wvb + (size_t)(DC) * 1024); \
        buf[S][3] = *(const short8*)(pkw + wvb + (size_t)(DC) * 1024 + 512); }

        K1L(0, 0)
        K1L(1, 1)
#pragma unroll
        for (int it = 0; it < 16; ++it) {
            if (it + 2 < 16) { K1L((it + 2) % 3, it + 2) }
            const int c = it % 3;
            const int co = it * 16 + h * 8;
            short8 jH = *(const short8*)&tq[0][l31][co];
            short8 jL = *(const short8*)&tq[1][l31][co];
            ak = mfma32(buf[c][0], jH, ak);
            ak = mfma32(buf[c][0], jL, ak);
            ak = mfma32(buf[c][1], jH, ak);
            av = mfma32(buf[c][2], jH, av);
            av = mfma32(buf[c][2], jL, av);
            av = mfma32(buf[c][3], jH, av);
        }
#undef K1L

        // ---- epilogue: packed-fragment scatter (zero-fill padded m) ----
        const int hp = (l31 >> 3) & 1, ee = l31 & 7, mcl = l31 >> 4;
        const size_t sb0 = ((size_t)b * 8 + dt) * 65536
                         + (size_t)(mt * 2 + mcl) * 2048 + (size_t)hp * 256 + ee;
        const bool v0 = (M0 + l31) < Mm;
#pragma unroll
        for (int r = 0; r < 16; ++r) {
            const int d31 = (r & 3) + ((r >> 2) << 3) + (h << 2);
            const size_t o = sb0 + (size_t)d31 * 8;
            u16 hh, ll;
            const float ek = v0 ? __expf(ak[r]) : 0.f;
            const float ev = v0 ? ek * av[r] : 0.f;
            split1(ek, hh, ll); pkb[o] = hh; pkb[o + 512] = ll;
            split1(ev, hh, ll); pkb[o + 1024] = hh; pkb[o + 1536] = ll;
        }
    } else {
        // ================= role 1: k2 (q0,q1 -> sq), two-pass =================
        const int nt = tile;
        const int dt = wv;
        floatx16 acc = zero16();

#pragma unroll
        for (int s = 0; s < 2; ++s) {
            const float* src = s ? q1 : q0;
            if (s) __syncthreads();   // prior pass's LDS reads done before restage
            // ---- stage (32 rows x 256 cols fp32) ----
#pragma unroll
            for (int it = 0; it < 2; ++it) {
                const int flat = (it * 512 + t) * 8;
                const int nl = flat >> 8, j0 = flat & 255;
                const int n = min(nt * 32 + nl, Nn - 1);
                const size_t o = ((size_t)b * Nn + n) * Dd + j0;
                float4 a = *(const float4*)&src[o];
                float4 c = *(const float4*)&src[o + 4];
                short8 hv, lv;
                split8(a, c, hv, lv);
                *(short8*)&tq[0][nl][j0] = hv;
                *(short8*)&tq[1][nl][j0] = lv;
            }
            __syncthreads();

            const size_t wb = (size_t)(16 + s * 8 + dt) * 16384 + (size_t)lane * 8;
            short8 buf[3][2];
#define K2L(S, DC) { \
            buf[S][0] = *(const short8*)(pkw + wb + (size_t)(DC) * 1024); \
            buf[S][1] = *(const short8*)(pkw + wb + (size_t)(DC) * 1024 + 512); }
            K2L(0, 0)
            K2L(1, 1)
#pragma unroll
            for (int it = 0; it < 16; ++it) {
                if (it + 2 < 16) { K2L((it + 2) % 3, it + 2) }
                const int c = it % 3;
                const int co = it * 16 + h * 8;
                short8 aH = *(const short8*)&tq[0][l31][co];
                short8 aL = *(const short8*)&tq[1][l31][co];
                acc = mfma32(aH, buf[c][0], acc);
                acc = mfma32(aH, buf[c][1], acc);
                acc = mfma32(aL, buf[c][0], acc);
            }
#undef K2L
        }

        // ---- epilogue: sq in fragment (C/D) layout, fully coalesced ----
        float* sp = sq + ((((size_t)b * 16 + nt) * 8 + dt) * 64 + lane) * 16;
#pragma unroll
        for (int r = 0; r < 16; ++r) {
            sp[r] = 1.0f / (1.0f + __expf(-acc[r]));
        }
    }
}

// ---------------------------------------------------------------------------
// K34: FUSED AAFM + score + softmax.  Block = (b,nt), 8 waves.
// T14 change vs round 8: phase-5 cost/mask loads hoisted into registers
// BEFORE the phase-4 MFMA loop (latency hides under 96 MFMAs); phase-4
// jbuf reduced to 2-set to offset the +64 VGPR stash.
// ---------------------------------------------------------------------------
__global__ __launch_bounds__(512) void k34(const float* __restrict__ cost,
                                           const float* __restrict__ mask,
                                           const float* __restrict__ alpha1,
                                           const float* __restrict__ alpha2,
                                           const float* __restrict__ lsc,
                                           const u16* __restrict__ pkb,
                                           const u16* __restrict__ pkj,
                                           const float* __restrict__ sq,
                                           float* __restrict__ out) {
    __shared__ u16 sh[16640];        // phase1-3: tile[32][520]; phase3+: aafm[16][2][512]
    __shared__ float pred[32][8];
    const int i = blockIdx.x;
    const int x = i & 7, j = i >> 3;
    const int nt = j & 15;
    const int b = ((j >> 4) << 3) + x;      // all nt of b on XCD x
    const int t = threadIdx.x;
    const int lane = t & 63, wv = t >> 6;   // wv 0..7
    const int l31 = lane & 31, h = lane >> 5;
    const int N0 = nt << 5;

    // ---- phase 1: expb tile (exp(-a1*ls*cost + mask), bf16, m>=500 zero) ----
    const float a1ls = alpha1[0] * lsc[0];
#pragma unroll
    for (int q = 0; q < 4; ++q) {
        const int flat = (q << 12) + (t << 3);
        const int nl = flat >> 9, m = flat & 511;
        const int n = min(N0 + nl, Nn - 1);
        const size_t o = ((size_t)b * Nn + n) * Mm + m;
        ushort4 w0 = {0, 0, 0, 0}, w1 = {0, 0, 0, 0};
        if (m <= 488) {
            float4 c0 = *(const float4*)&cost[o];
            float4 c1 = *(const float4*)&cost[o + 4];
            float4 k0 = *(const float4*)&mask[o];
            float4 k1 = *(const float4*)&mask[o + 4];
            w0.x = bf16rtn(__expf(fmaf(-a1ls, c0.x, k0.x)));
            w0.y = bf16rtn(__expf(fmaf(-a1ls, c0.y, k0.y)));
            w0.z = bf16rtn(__expf(fmaf(-a1ls, c0.z, k0.z)));
            w0.w = bf16rtn(__expf(fmaf(-a1ls, c0.w, k0.w)));
            w1.x = bf16rtn(__expf(fmaf(-a1ls, c1.x, k1.x)));
            w1.y = bf16rtn(__expf(fmaf(-a1ls, c1.y, k1.y)));
            w1.z = bf16rtn(__expf(fmaf(-a1ls, c1.z, k1.z)));
            w1.w = bf16rtn(__expf(fmaf(-a1ls, c1.w, k1.w)));
        } else if (m == 496) {
            float4 c0 = *(const float4*)&cost[o];
            float4 k0 = *(const float4*)&mask[o];
            w0.x = bf16rtn(__expf(fmaf(-a1ls, c0.x, k0.x)));
            w0.y = bf16rtn(__expf(fmaf(-a1ls, c0.y, k0.y)));
            w0.z = bf16rtn(__expf(fmaf(-a1ls, c0.z, k0.z)));
            w0.w = bf16rtn(__expf(fmaf(-a1ls, c0.w, k0.w)));
        }
        *(ushort4*)&sh[nl * 520 + m] = w0;
        *(ushort4*)&sh[nl * 520 + m + 4] = w1;
    }
    __syncthreads();

    // ---- phase 2: dn/nm accumulation, wave wv -> dt = wv ----
    const size_t bbase = ((size_t)b * 8 + wv) * 65536 + (size_t)lane * 8;
    floatx16 dn = zero16(), nm = zero16();
    short8 buf[3][4];
#define K3L(S, MC) { \
    buf[S][0] = *(const short8*)(pkb + bbase + (size_t)(MC) * 2048); \
    buf[S][1] = *(const short8*)(pkb + bbase + (size_t)(MC) * 2048 + 512); \
    buf[S][2] = *(const short8*)(pkb + bbase + (size_t)(MC) * 2048 + 1024); \
    buf[S][3] = *(const short8*)(pkb + bbase + (size_t)(MC) * 2048 + 1536); }

    K3L(0, 0)
    K3L(1, 1)
#pragma unroll
    for (int mc = 0; mc < 32; ++mc) {
        if (mc + 2 < 32) { K3L((mc + 2) % 3, mc + 2) }
        const int c = mc % 3;
        short8 aa = *(const short8*)&sh[l31 * 520 + mc * 16 + h * 8];
        dn = mfma32(aa, buf[c][0], dn);
        dn = mfma32(aa, buf[c][1], dn);
        nm = mfma32(aa, buf[c][2], nm);
        nm = mfma32(aa, buf[c][3], nm);
    }
#undef K3L
    __syncthreads();   // all tile reads done; safe to overwrite with aafm

    // ---- phase 3: aafm -> bf16 H/L A-fragments in LDS ----
    {
        const float* sp = sq + ((((size_t)b * 16 + nt) * 8 + wv) * 64 + lane) * 16;
        const int hp = (l31 >> 3) & 1, ee = l31 & 7;
        const int fo = (wv * 2 + (l31 >> 4)) * 1024 + hp * 256 + ee;
#pragma unroll
        for (int r = 0; r < 16; ++r) {
            const int n31 = (r & 3) + ((r >> 2) << 3) + (h << 2);
            const float d0 = dn[r];
            const float w0 = (d0 != 0.f) ? nm[r] / d0 : 0.f;
            u16 hh, ll;
            split1(sp[r] * w0, hh, ll);
            sh[fo + n31 * 8] = hh;
            sh[fo + 512 + n31 * 8] = ll;
        }
    }
    __syncthreads();

    // ---- T14 hoist: phase-5 cost/mask -> registers; hides under phase 4 ----
    const int m0g = wv * 64 + l31;
    const int m1g = m0g + 32;
    const size_t cb = (size_t)b * Nn * Mm;
    float cst0[16], msk0[16], cst1[16], msk1[16];
#pragma unroll
    for (int r = 0; r < 16; ++r) {
        const int row = (r & 3) + ((r >> 2) << 3) + (h << 2);
        const int nc = min(N0 + row, Nn - 1);
        const size_t o = cb + (size_t)nc * Mm + m0g;
        cst0[r] = cost[o]; msk0[r] = mask[o];
        if (m1g < Mm) { cst1[r] = cost[o + 32]; msk1[r] = mask[o + 32]; }
        else { cst1[r] = 0.f; msk1[r] = 0.f; }
    }

    // ---- phase 4: score GEMM; wave wv -> m block [wv*64, wv*64+64) ----
    const u16* jb0p = pkj + ((size_t)b * 16 + wv * 2) * 16384 + (size_t)lane * 8;
    const u16* jb1p = jb0p + 16384;

    floatx16 acc0 = zero16(), acc1 = zero16();
    short8 jbuf[2][4];
#define K4L(S, DC) { \
    jbuf[S][0] = *(const short8*)(jb0p + (size_t)(DC) * 1024); \
    jbuf[S][1] = *(const short8*)(jb0p + (size_t)(DC) * 1024 + 512); \
    jbuf[S][2] = *(const short8*)(jb1p + (size_t)(DC) * 1024); \
    jbuf[S][3] = *(const short8*)(jb1p + (size_t)(DC) * 1024 + 512); }

    K4L(0, 0)
#pragma unroll
    for (int dc = 0; dc < 16; ++dc) {
        const int cur = dc & 1;
        if (dc + 1 < 16) { K4L(cur ^ 1, dc + 1) }
        short8 aH = *(const short8*)&sh[dc * 1024 + lane * 8];
        short8 aL = *(const short8*)&sh[dc * 1024 + 512 + lane * 8];
        acc0 = mfma32(aH, jbuf[cur][0], acc0);
        acc0 = mfma32(aH, jbuf[cur][1], acc0);
        acc0 = mfma32(aL, jbuf[cur][0], acc0);
        acc1 = mfma32(aH, jbuf[cur][2], acc1);
        acc1 = mfma32(aH, jbuf[cur][3], acc1);
        acc1 = mfma32(aL, jbuf[cur][2], acc1);
    }
#undef K4L

    // ---- phase 5: logits (cost/mask from registers) ----
    float lg0[16], lg1[16];
    const float a2ls = alpha2[0] * lsc[0];
#pragma unroll
    for (int r = 0; r < 16; ++r) {
        const int row = (r & 3) + ((r >> 2) << 3) + (h << 2);
        const int n = N0 + row;
        if (n < Nn) {
            lg0[r] = LOGIT_CLIP * fast_tanh(fmaf(-a2ls, cst0[r], acc0[r] * INV_SQRT_D)) + msk0[r];
            if (m1g < Mm) {
                lg1[r] = LOGIT_CLIP * fast_tanh(fmaf(-a2ls, cst1[r], acc1[r] * INV_SQRT_D)) + msk1[r];
            } else lg1[r] = -1e30f;
        } else { lg0[r] = -1e30f; lg1[r] = -1e30f; }
    }

    // ---- row max: butterfly within 32-lane half, then cross-wave via LDS ----
    float rm[16];
#pragma unroll
    for (int r = 0; r < 16; ++r) rm[r] = fmaxf(lg0[r], lg1[r]);
#pragma unroll
    for (int d = 1; d < 32; d <<= 1)
#pragma unroll
        for (int r = 0; r < 16; ++r) rm[r] = fmaxf(rm[r], __shfl_xor(rm[r], d));
    if (l31 == 0) {
#pragma unroll
        for (int r = 0; r < 16; ++r)
            pred[(r & 3) + ((r >> 2) << 3) + (h << 2)][wv] = rm[r];
    }
    __syncthreads();
    float fm[16];
#pragma unroll
    for (int r = 0; r < 16; ++r) {
        const int row = (r & 3) + ((r >> 2) << 3) + (h << 2);
        float v = pred[row][0];
#pragma unroll
        for (int w = 1; w < 8; ++w) v = fmaxf(v, pred[row][w]);
        fm[r] = v;
    }
    __syncthreads();

    // ---- exp + row sum ----
    float sm[16];
#pragma unroll
    for (int r = 0; r < 16; ++r) {
        lg0[r] = __expf(lg0[r] - fm[r]);
        lg1[r] = __expf(lg1[r] - fm[r]);
        sm[r] = lg0[r] + lg1[r];
    }
#pragma unroll
    for (int d = 1; d < 32; d <<= 1)
#pragma unroll
        for (int r = 0; r < 16; ++r) sm[r] += __shfl_xor(sm[r], d);
    if (l31 == 0) {
#pragma unroll
        for (int r = 0; r < 16; ++r)
            pred[(r & 3) + ((r >> 2) << 3) + (h << 2)][wv] = sm[r];
    }
    __syncthreads();

    // ---- normalize + store ----
#pragma unroll
    for (int r = 0; r < 16; ++r) {
        const int row = (r & 3) + ((r >> 2) << 3) + (h << 2);
        const int n = N0 + row;
        if (n < Nn) {
            float s = pred[row][0];
#pragma unroll
            for (int w = 1; w < 8; ++w) s += pred[row][w];
            const float inv = 1.0f / s;
            const size_t o = cb + (size_t)n * Mm + m0g;
            out[o] = lg0[r] * inv;
            if (m1g < Mm) out[o + 32] = lg1[r] * inv;
        }
    }
}

// ---------------------------------------------------------------------------
extern "C" void kernel_launch(void* const* d_in, const int* in_sizes, int n_in,
                              void* d_out, int out_size, void* d_ws, size_t ws_size,
                              hipStream_t stream) {
    const float* q0        = (const float*)d_in[0];
    const float* jobs      = (const float*)d_in[1];
    const float* q1        = (const float*)d_in[2];
    const float* cost      = (const float*)d_in[3];
    const float* log_scale = (const float*)d_in[4];
    const float* mask      = (const float*)d_in[5];
    const float* Wq0       = (const float*)d_in[6];
    const float* Wq1       = (const float*)d_in[7];
    const float* Wk        = (const float*)d_in[8];
    const float* Wv        = (const float*)d_in[9];
    const float* alpha1    = (const float*)d_in[10];
    const float* alpha2    = (const float*)d_in[11];
    float* out = (float*)d_out;

    const size_t PK_SZ  = (size_t)Bc * 16 * 16384;     //  8,388,608 u16
    const size_t PKW_SZ = (size_t)4 * 8 * 16384;       //    524,288 u16
    const size_t PKB_SZ = (size_t)Bc * 8 * 65536;      // 16,777,216 u16

    // ws layout (u16 units): [PKJ | PKW | PKB | SQ_PK(fp32)]  ~68 MB
    u16* ws   = (u16*)d_ws;
    u16* pkj  = ws;
    u16* pkw  = ws + PK_SZ;
    u16* pkb  = pkw + PKW_SZ;
    float* sq = (float*)(pkb + PKB_SZ);
    (void)ws_size;

    k0w_pk<<<dim3(32, 4), dim3(256), 0, stream>>>(Wk, Wv, Wq0, Wq1, pkw);
    k12<<<dim3(16, 32, 2), dim3(512), 0, stream>>>(jobs, q0, q1, pkw, pkj, pkb, sq);
    k34<<<512, dim3(512), 0, stream>>>(cost, mask, alpha1, alpha2, log_scale,
                                       pkb, pkj, sq, out);
}

// Round 10
// 262.282 us; speedup vs baseline: 1.0363x; 1.0363x over previous
//
#include <hip/hip_runtime.h>
#include <math.h>

using u16 = unsigned short;
typedef __attribute__((ext_vector_type(8))) short short8;
typedef __attribute__((ext_vector_type(16))) float floatx16;

constexpr int Bc = 32, Nn = 500, Mm = 500, Dd = 256;
constexpr float LOGIT_CLIP = 10.0f;
constexpr float INV_SQRT_D = 1.0f / 16.0f;

__device__ __forceinline__ floatx16 mfma32(short8 a, short8 b, floatx16 c) {
    return __builtin_amdgcn_mfma_f32_32x32x16_bf16(a, b, c, 0, 0, 0);
}

__device__ __forceinline__ floatx16 zero16() {
    floatx16 v = {0.f,0.f,0.f,0.f,0.f,0.f,0.f,0.f,0.f,0.f,0.f,0.f,0.f,0.f,0.f,0.f};
    return v;
}

// split fp32 x into bf16 hi (RTN) + bf16 lo (RTN of residual): x ~= hi + lo
__device__ __forceinline__ void split1(float x, u16& h, u16& l) {
    unsigned u = __float_as_uint(x);
    unsigned rh = (u + 0x7FFFu + ((u >> 16) & 1u)) & 0xFFFF0000u;
    float fh = __uint_as_float(rh);
    float fl = x - fh;
    unsigned ul = __float_as_uint(fl);
    unsigned rl = ul + 0x7FFFu + ((ul >> 16) & 1u);
    h = (u16)(rh >> 16);
    l = (u16)(rl >> 16);
}

__device__ __forceinline__ u16 bf16rtn(float x) {
    unsigned u = __float_as_uint(x);
    return (u16)((u + 0x7FFFu + ((u >> 16) & 1u)) >> 16);
}

__device__ __forceinline__ float fast_tanh(float x) {
    return 1.0f - 2.0f / (__expf(2.0f * x) + 1.0f);
}

__device__ __forceinline__ void split8(const float4& a, const float4& c,
                                       short8& hv, short8& lv) {
    u16 hh, ll;
    split1(a.x, hh, ll); hv[0] = (short)hh; lv[0] = (short)ll;
    split1(a.y, hh, ll); hv[1] = (short)hh; lv[1] = (short)ll;
    split1(a.z, hh, ll); hv[2] = (short)hh; lv[2] = (short)ll;
    split1(a.w, hh, ll); hv[3] = (short)hh; lv[3] = (short)ll;
    split1(c.x, hh, ll); hv[4] = (short)hh; lv[4] = (short)ll;
    split1(c.y, hh, ll); hv[5] = (short)hh; lv[5] = (short)ll;
    split1(c.z, hh, ll); hv[6] = (short)hh; lv[6] = (short)ll;
    split1(c.w, hh, ll); hv[7] = (short)hh; lv[7] = (short)ll;
}

// ===========================================================================
// Packed fragment layouts (u16 units), fragment = [lane(64)][e(8)] = 512 u16:
//   element (row r, col d) lives at lane=((d>>3)&1)<<5 | (r&31), e = d&7.
//   tile stride: 16 dc-chunks x 2 arr(H/L) x 512 = 16384 u16 per 32-row tile.
// PKW [w(4)][dt(8)]  : weights,  w = {Wk,Wv,Wq0,Wq1}, rows = out-dim.
// PKJ [b][mt(16)]    : jobs,   rows m (zero-padded to 512).
// PKB [b][dt(8)][mc(32)][arr(4: ekH,ekL,ekvH,ekvL)][512] : ek/ekv transposed.
// SQ_PK [b][nt(16)][dt(8)][lane(64)][r(16)] fp32 : sigmoid(q), C/D-fragment
//   layout (same (r,lane)->(row,col) map as the MFMA accumulator).
// ===========================================================================

// ---------------------------------------------------------------------------
// K0w_pk: weights fp32 -> packed bf16 hi/lo fragments
// ---------------------------------------------------------------------------
__global__ __launch_bounds__(256) void k0w_pk(const float* __restrict__ s0,
                                              const float* __restrict__ s1,
                                              const float* __restrict__ s2,
                                              const float* __restrict__ s3,
                                              u16* __restrict__ pkw) {
    const float* s = blockIdx.y == 0 ? s0 : blockIdx.y == 1 ? s1 :
                     blockIdx.y == 2 ? s2 : s3;
    const int w = blockIdx.y;
    const int flat = (blockIdx.x * 256 + threadIdx.x) * 8;   // 0..65535
    const int i = flat >> 8, j0 = flat & 255;
    float4 a = *(const float4*)&s[flat];
    float4 c = *(const float4*)&s[flat + 4];
    short8 hv, lv;
    split8(a, c, hv, lv);
    const int dt = i >> 5, i31 = i & 31, dc = j0 >> 4, hp = (j0 >> 3) & 1;
    const size_t off = (size_t)(w * 8 + dt) * 16384 + (size_t)dc * 1024
                     + (size_t)((hp << 5) | i31) * 8;
    *(short8*)&pkw[off] = hv;
    *(short8*)&pkw[off + 512] = lv;
}

// ---------------------------------------------------------------------------
// K1: k/v = jobs@Wk^T/Wv^T, FUSED jobs-packing.
// Block (mt,b), 512 thr / 8 waves:
//   phase A: stage raw jobs rows -> hi/lo LDS transpose (rows >= 500 zeroed);
//   phase B: write pkj tile to global from LDS (coalesced);
//   phase C: GEMM, wave wv -> dt=wv; B-fragments from LDS, weights register-
//            pipelined;
//   phase D (NEW): epilogue via LDS staging -- each wave scatters its ek/ekv
//            fragments into LDS (2B LDS stores, cheap), then all threads
//            store contiguous short8 lines to pkb (full-line coalesced
//            writes; removes the 2-byte global scatter's RMW amplification).
//            Two 4-wave halves (tile = 64KB > 33KB LDS buffer).
// ---------------------------------------------------------------------------
__global__ __launch_bounds__(512) void k1_kv(const float* __restrict__ jobs,
                                             const u16* __restrict__ pkw,
                                             u16* __restrict__ pkj,
                                             u16* __restrict__ pkb) {
    __shared__ u16 tq[2][32][264];   // [H|L][row][col(+pad)]; reused as epi
    const int t = threadIdx.x;
    const int lane = t & 63, wv = t >> 6;   // wv 0..7
    const int l31 = lane & 31, h = lane >> 5;
    const int mt = blockIdx.x;              // 0..15, M0 = mt*32
    const int b = blockIdx.y;
    const int M0 = mt * 32;

    // ---- phase A: stage jobs tile (32 rows x 256 cols fp32) ----
#pragma unroll
    for (int it = 0; it < 2; ++it) {
        const int flat = (it * 512 + t) * 8;    // 0..8191
        const int nl = flat >> 8, j0 = flat & 255;
        const int m = M0 + nl;
        short8 hv = {0,0,0,0,0,0,0,0}, lv = {0,0,0,0,0,0,0,0};
        if (m < Mm) {
            const size_t o = ((size_t)b * Mm + m) * Dd + j0;
            float4 a = *(const float4*)&jobs[o];
            float4 c = *(const float4*)&jobs[o + 4];
            split8(a, c, hv, lv);
        }
        *(short8*)&tq[0][nl][j0] = hv;
        *(short8*)&tq[1][nl][j0] = lv;
    }
    __syncthreads();

    // ---- phase B: pkj tile write (fragment layout, coalesced) ----
    {
        u16* dst = pkj + (size_t)(b * 16 + mt) * 16384;
#pragma unroll
        for (int it = 0; it < 4; ++it) {
            const int u = it * 512 + t;        // 0..2047 short8s
            const int dc = u >> 7;
            const int rem = u & 127;
            const int sel = rem >> 6;
            const int idx = rem & 63;
            const int hp = idx >> 5, r31 = idx & 31;
            short8 v = *(const short8*)&tq[sel][r31][dc * 16 + hp * 8];
            *(short8*)&dst[(size_t)dc * 1024 + sel * 512 + (size_t)idx * 8] = v;
        }
    }

    // ---- phase C: GEMM, wave wv -> dt = wv ----
    const int dt = wv;
    const size_t wk  = (size_t)dt * 16384 + (size_t)lane * 8;         // Wk
    const size_t wvb = (size_t)(8 + dt) * 16384 + (size_t)lane * 8;   // Wv

    floatx16 ak = zero16(), av = zero16();

    short8 buf[3][4];
#define K1L(S, DC) { \
    buf[S][0] = *(const short8*)(pkw + wk  + (size_t)(DC) * 1024); \
    buf[S][1] = *(const short8*)(pkw + wk  + (size_t)(DC) * 1024 + 512); \
    buf[S][2] = *(const short8*)(pkw + wvb + (size_t)(DC) * 1024); \
    buf[S][3] = *(const short8*)(pkw + wvb + (size_t)(DC) * 1024 + 512); }

    K1L(0, 0)
    K1L(1, 1)
#pragma unroll
    for (int it = 0; it < 16; ++it) {
        if (it + 2 < 16) { K1L((it + 2) % 3, it + 2) }
        const int c = it % 3;
        const int co = it * 16 + h * 8;
        short8 jH = *(const short8*)&tq[0][l31][co];
        short8 jL = *(const short8*)&tq[1][l31][co];
        ak = mfma32(buf[c][0], jH, ak);
        ak = mfma32(buf[c][0], jL, ak);
        ak = mfma32(buf[c][1], jH, ak);
        av = mfma32(buf[c][2], jH, av);
        av = mfma32(buf[c][2], jL, av);
        av = mfma32(buf[c][3], jH, av);
    }
#undef K1L
    __syncthreads();   // all tq reads complete; reuse LDS as epi buffer

    // ---- phase D: LDS-staged epilogue, two 4-wave halves ----
    // epi layout: [dtp(4)][mcl(2)][arr(4)][frag 512 u16], 16384 u16 total.
    u16* epi = &tq[0][0][0];
    const int hp = (l31 >> 3) & 1, ee = l31 & 7, mcl = l31 >> 4;
    const bool v0 = (M0 + l31) < Mm;
#pragma unroll
    for (int half = 0; half < 2; ++half) {
        if ((wv >> 2) == half) {
            const int dtp = wv & 3;
            const int fb = dtp * 4096 + mcl * 2048 + hp * 256 + ee;
#pragma unroll
            for (int r = 0; r < 16; ++r) {
                const int d31 = (r & 3) + ((r >> 2) << 3) + (h << 2);
                u16 hh, ll;
                const float ek = v0 ? __expf(ak[r]) : 0.f;
                const float ev = v0 ? ek * av[r] : 0.f;
                split1(ek, hh, ll);
                epi[fb + d31 * 8] = hh;
                epi[fb + 512 + d31 * 8] = ll;
                split1(ev, hh, ll);
                epi[fb + 1024 + d31 * 8] = hh;
                epi[fb + 1536 + d31 * 8] = ll;
            }
        }
        __syncthreads();
        // cooperative coalesced store of this half's 16384 u16 (2048 short8)
#pragma unroll
        for (int it = 0; it < 4; ++it) {
            const int u = it * 512 + t;
            const int dtp = u >> 9;
            const int rem = u & 511;
            const int mc2 = rem >> 8;
            const int rem2 = rem & 255;
            const int arr = rem2 >> 6;
            const int idx = rem2 & 63;
            short8 v = *(const short8*)&epi[dtp * 4096 + mc2 * 2048
                                            + arr * 512 + idx * 8];
            *(short8*)&pkb[((size_t)b * 8 + half * 4 + dtp) * 65536
                           + (size_t)(mt * 2 + mc2) * 2048
                           + (size_t)arr * 512 + (size_t)idx * 8] = v;
        }
        if (half == 0) __syncthreads();
    }
}

// ---------------------------------------------------------------------------
// K2: sq = sigmoid(q0@Wq0^T + q1@Wq1^T).  FUSED q-staging, 8 waves:
// block (nt,b) stages raw fp32 q0/q1 rows -> hi/lo LDS transpose; wave wv
// owns dt=wv (1 acc).  Weights via 3-set register pipeline.
// Output sq in SQ_PK fragment layout.
// ---------------------------------------------------------------------------
__global__ __launch_bounds__(512) void k2_q(const float* __restrict__ q0,
                                            const float* __restrict__ q1,
                                            const u16* __restrict__ pkw,
                                            float* __restrict__ sq) {
    __shared__ u16 tq[4][32][264];   // [q0h|q0l|q1h|q1l][row][col(+pad)]
    const int t = threadIdx.x;
    const int lane = t & 63, wv = t >> 6;   // wv 0..7
    const int l31 = lane & 31, h = lane >> 5;
    const int b = blockIdx.y;
    const int nt = blockIdx.x;              // N0 = nt*32

    // ---- phase 1: stage q0,q1 (32 rows x 256 cols fp32 each) ----
#pragma unroll
    for (int s = 0; s < 2; ++s) {
        const float* src = s ? q1 : q0;
#pragma unroll
        for (int it = 0; it < 2; ++it) {
            const int flat = (it * 512 + t) * 8;    // 0..8191
            const int nl = flat >> 8, j0 = flat & 255;
            const int n = min(nt * 32 + nl, Nn - 1);
            const size_t o = ((size_t)b * Nn + n) * Dd + j0;
            float4 a = *(const float4*)&src[o];
            float4 c = *(const float4*)&src[o + 4];
            short8 hv, lv;
            split8(a, c, hv, lv);
            *(short8*)&tq[s * 2][nl][j0] = hv;
            *(short8*)&tq[s * 2 + 1][nl][j0] = lv;
        }
    }
    __syncthreads();

    const int dt = wv;
    const size_t w0b = (size_t)(16 + dt) * 16384 + (size_t)lane * 8;  // Wq0
    const size_t w1b = (size_t)(24 + dt) * 16384 + (size_t)lane * 8;  // Wq1

    floatx16 acc = zero16();

    short8 buf[3][4];
#define K2L(S, DC) { \
    buf[S][0] = *(const short8*)(pkw + w0b + (size_t)(DC) * 1024); \
    buf[S][1] = *(const short8*)(pkw + w0b + (size_t)(DC) * 1024 + 512); \
    buf[S][2] = *(const short8*)(pkw + w1b + (size_t)(DC) * 1024); \
    buf[S][3] = *(const short8*)(pkw + w1b + (size_t)(DC) * 1024 + 512); }

    K2L(0, 0)
    K2L(1, 1)
#pragma unroll
    for (int it = 0; it < 16; ++it) {
        if (it + 2 < 16) { K2L((it + 2) % 3, it + 2) }
        const int c = it % 3;
        const int co = it * 16 + h * 8;
        short8 a0h = *(const short8*)&tq[0][l31][co];
        short8 a0l = *(const short8*)&tq[1][l31][co];
        short8 a1h = *(const short8*)&tq[2][l31][co];
        short8 a1l = *(const short8*)&tq[3][l31][co];
        acc = mfma32(a0h, buf[c][0], acc);
        acc = mfma32(a0h, buf[c][1], acc);
        acc = mfma32(a0l, buf[c][0], acc);
        acc = mfma32(a1h, buf[c][2], acc);
        acc = mfma32(a1h, buf[c][3], acc);
        acc = mfma32(a1l, buf[c][2], acc);
    }
#undef K2L

    // ---- epilogue: sq in fragment (C/D) layout, fully coalesced ----
    float* sp = sq + ((((size_t)b * 16 + nt) * 8 + dt) * 64 + lane) * 16;
#pragma unroll
    for (int r = 0; r < 16; ++r) {
        sp[r] = 1.0f / (1.0f + __expf(-acc[r]));
    }
}

// ---------------------------------------------------------------------------
// K34: FUSED AAFM + score + softmax.  Block = (b,nt), 8 waves.
// (round-8 version: T14 hoist reverted -- it cost VGPR 40->76 and +4.7us)
// ---------------------------------------------------------------------------
__global__ __launch_bounds__(512) void k34(const float* __restrict__ cost,
                                           const float* __restrict__ mask,
                                           const float* __restrict__ alpha1,
                                           const float* __restrict__ alpha2,
                                           const float* __restrict__ lsc,
                                           const u16* __restrict__ pkb,
                                           const u16* __restrict__ pkj,
                                           const float* __restrict__ sq,
                                           float* __restrict__ out) {
    __shared__ u16 sh[16640];        // phase1-3: tile[32][520]; phase3+: aafm[16][2][512]
    __shared__ float pred[32][8];
    const int i = blockIdx.x;
    const int x = i & 7, j = i >> 3;
    const int nt = j & 15;
    const int b = ((j >> 4) << 3) + x;      // all nt of b on XCD x
    const int t = threadIdx.x;
    const int lane = t & 63, wv = t >> 6;   // wv 0..7
    const int l31 = lane & 31, h = lane >> 5;
    const int N0 = nt << 5;

    // ---- phase 1: expb tile (exp(-a1*ls*cost + mask), bf16, m>=500 zero) ----
    const float a1ls = alpha1[0] * lsc[0];
#pragma unroll
    for (int q = 0; q < 4; ++q) {
        const int flat = (q << 12) + (t << 3);
        const int nl = flat >> 9, m = flat & 511;
        const int n = min(N0 + nl, Nn - 1);
        const size_t o = ((size_t)b * Nn + n) * Mm + m;
        ushort4 w0 = {0, 0, 0, 0}, w1 = {0, 0, 0, 0};
        if (m <= 488) {
            float4 c0 = *(const float4*)&cost[o];
            float4 c1 = *(const float4*)&cost[o + 4];
            float4 k0 = *(const float4*)&mask[o];
            float4 k1 = *(const float4*)&mask[o + 4];
            w0.x = bf16rtn(__expf(fmaf(-a1ls, c0.x, k0.x)));
            w0.y = bf16rtn(__expf(fmaf(-a1ls, c0.y, k0.y)));
            w0.z = bf16rtn(__expf(fmaf(-a1ls, c0.z, k0.z)));
            w0.w = bf16rtn(__expf(fmaf(-a1ls, c0.w, k0.w)));
            w1.x = bf16rtn(__expf(fmaf(-a1ls, c1.x, k1.x)));
            w1.y = bf16rtn(__expf(fmaf(-a1ls, c1.y, k1.y)));
            w1.z = bf16rtn(__expf(fmaf(-a1ls, c1.z, k1.z)));
            w1.w = bf16rtn(__expf(fmaf(-a1ls, c1.w, k1.w)));
        } else if (m == 496) {
            float4 c0 = *(const float4*)&cost[o];
            float4 k0 = *(const float4*)&mask[o];
            w0.x = bf16rtn(__expf(fmaf(-a1ls, c0.x, k0.x)));
            w0.y = bf16rtn(__expf(fmaf(-a1ls, c0.y, k0.y)));
            w0.z = bf16rtn(__expf(fmaf(-a1ls, c0.z, k0.z)));
            w0.w = bf16rtn(__expf(fmaf(-a1ls, c0.w, k0.w)));
        }
        *(ushort4*)&sh[nl * 520 + m] = w0;
        *(ushort4*)&sh[nl * 520 + m + 4] = w1;
    }
    __syncthreads();

    // ---- phase 2: dn/nm accumulation, wave wv -> dt = wv ----
    const size_t bbase = ((size_t)b * 8 + wv) * 65536 + (size_t)lane * 8;
    floatx16 dn = zero16(), nm = zero16();
    short8 buf[3][4];
#define K3L(S, MC) { \
    buf[S][0] = *(const short8*)(pkb + bbase + (size_t)(MC) * 2048); \
    buf[S][1] = *(const short8*)(pkb + bbase + (size_t)(MC) * 2048 + 512); \
    buf[S][2] = *(const short8*)(pkb + bbase + (size_t)(MC) * 2048 + 1024); \
    buf[S][3] = *(const short8*)(pkb + bbase + (size_t)(MC) * 2048 + 1536); }

    K3L(0, 0)
    K3L(1, 1)
#pragma unroll
    for (int mc = 0; mc < 32; ++mc) {
        if (mc + 2 < 32) { K3L((mc + 2) % 3, mc + 2) }
        const int c = mc % 3;
        short8 aa = *(const short8*)&sh[l31 * 520 + mc * 16 + h * 8];
        dn = mfma32(aa, buf[c][0], dn);
        dn = mfma32(aa, buf[c][1], dn);
        nm = mfma32(aa, buf[c][2], nm);
        nm = mfma32(aa, buf[c][3], nm);
    }
#undef K3L
    __syncthreads();   // all tile reads done; safe to overwrite with aafm

    // ---- phase 3: aafm -> bf16 H/L A-fragments in LDS ----
    {
        const float* sp = sq + ((((size_t)b * 16 + nt) * 8 + wv) * 64 + lane) * 16;
        const int hp = (l31 >> 3) & 1, ee = l31 & 7;
        const int fo = (wv * 2 + (l31 >> 4)) * 1024 + hp * 256 + ee;
#pragma unroll
        for (int r = 0; r < 16; ++r) {
            const int n31 = (r & 3) + ((r >> 2) << 3) + (h << 2);
            const float d0 = dn[r];
            const float w0 = (d0 != 0.f) ? nm[r] / d0 : 0.f;
            u16 hh, ll;
            split1(sp[r] * w0, hh, ll);
            sh[fo + n31 * 8] = hh;
            sh[fo + 512 + n31 * 8] = ll;
        }
    }
    __syncthreads();

    // ---- phase 4: score GEMM; wave wv -> m block [wv*64, wv*64+64) ----
    const u16* jb0p = pkj + ((size_t)b * 16 + wv * 2) * 16384 + (size_t)lane * 8;
    const u16* jb1p = jb0p + 16384;
    const int m0g = wv * 64 + l31;
    const int m1g = m0g + 32;

    floatx16 acc0 = zero16(), acc1 = zero16();
    short8 jbuf[3][4];
#define K4L(S, DC) { \
    jbuf[S][0] = *(const short8*)(jb0p + (size_t)(DC) * 1024); \
    jbuf[S][1] = *(const short8*)(jb0p + (size_t)(DC) * 1024 + 512); \
    jbuf[S][2] = *(const short8*)(jb1p + (size_t)(DC) * 1024); \
    jbuf[S][3] = *(const short8*)(jb1p + (size_t)(DC) * 1024 + 512); }

    K4L(0, 0)
    K4L(1, 1)
#pragma unroll
    for (int dc = 0; dc < 16; ++dc) {
        if (dc + 2 < 16) { K4L((dc + 2) % 3, dc + 2) }
        const int c = dc % 3;
        short8 aH = *(const short8*)&sh[dc * 1024 + lane * 8];
        short8 aL = *(const short8*)&sh[dc * 1024 + 512 + lane * 8];
        acc0 = mfma32(aH, jbuf[c][0], acc0);
        acc0 = mfma32(aH, jbuf[c][1], acc0);
        acc0 = mfma32(aL, jbuf[c][0], acc0);
        acc1 = mfma32(aH, jbuf[c][2], acc1);
        acc1 = mfma32(aH, jbuf[c][3], acc1);
        acc1 = mfma32(aL, jbuf[c][2], acc1);
    }
#undef K4L

    // ---- phase 5: logits ----
    float lg0[16], lg1[16];
    const float a2ls = alpha2[0] * lsc[0];
    const size_t cb = (size_t)b * Nn * Mm;
#pragma unroll
    for (int r = 0; r < 16; ++r) {
        const int row = (r & 3) + ((r >> 2) << 3) + (h << 2);
        const int n = N0 + row;
        if (n < Nn) {
            const size_t o = cb + (size_t)n * Mm + m0g;
            lg0[r] = LOGIT_CLIP * fast_tanh(fmaf(-a2ls, cost[o], acc0[r] * INV_SQRT_D)) + mask[o];
            if (m1g < Mm) {
                const size_t o1 = o + 32;
                lg1[r] = LOGIT_CLIP * fast_tanh(fmaf(-a2ls, cost[o1], acc1[r] * INV_SQRT_D)) + mask[o1];
            } else lg1[r] = -1e30f;
        } else { lg0[r] = -1e30f; lg1[r] = -1e30f; }
    }

    // ---- row max: butterfly within 32-lane half, then cross-wave via LDS ----
    float rm[16];
#pragma unroll
    for (int r = 0; r < 16; ++r) rm[r] = fmaxf(lg0[r], lg1[r]);
#pragma unroll
    for (int d = 1; d < 32; d <<= 1)
#pragma unroll
        for (int r = 0; r < 16; ++r) rm[r] = fmaxf(rm[r], __shfl_xor(rm[r], d));
    if (l31 == 0) {
#pragma unroll
        for (int r = 0; r < 16; ++r)
            pred[(r & 3) + ((r >> 2) << 3) + (h << 2)][wv] = rm[r];
    }
    __syncthreads();
    float fm[16];
#pragma unroll
    for (int r = 0; r < 16; ++r) {
        const int row = (r & 3) + ((r >> 2) << 3) + (h << 2);
        float v = pred[row][0];
#pragma unroll
        for (int w = 1; w < 8; ++w) v = fmaxf(v, pred[row][w]);
        fm[r] = v;
    }
    __syncthreads();

    // ---- exp + row sum ----
    float sm[16];
#pragma unroll
    for (int r = 0; r < 16; ++r) {
        lg0[r] = __expf(lg0[r] - fm[r]);
        lg1[r] = __expf(lg1[r] - fm[r]);
        sm[r] = lg0[r] + lg1[r];
    }
#pragma unroll
    for (int d = 1; d < 32; d <<= 1)
#pragma unroll
        for (int r = 0; r < 16; ++r) sm[r] += __shfl_xor(sm[r], d);
    if (l31 == 0) {
#pragma unroll
        for (int r = 0; r < 16; ++r)
            pred[(r & 3) + ((r >> 2) << 3) + (h << 2)][wv] = sm[r];
    }
    __syncthreads();

    // ---- normalize + store ----
#pragma unroll
    for (int r = 0; r < 16; ++r) {
        const int row = (r & 3) + ((r >> 2) << 3) + (h << 2);
        const int n = N0 + row;
        if (n < Nn) {
            float s = pred[row][0];
#pragma unroll
            for (int w = 1; w < 8; ++w) s += pred[row][w];
            const float inv = 1.0f / s;
            const size_t o = cb + (size_t)n * Mm + m0g;
            out[o] = lg0[r] * inv;
            if (m1g < Mm) out[o + 32] = lg1[r] * inv;
        }
    }
}

// ---------------------------------------------------------------------------
extern "C" void kernel_launch(void* const* d_in, const int* in_sizes, int n_in,
                              void* d_out, int out_size, void* d_ws, size_t ws_size,
                              hipStream_t stream) {
    const float* q0        = (const float*)d_in[0];
    const float* jobs      = (const float*)d_in[1];
    const float* q1        = (const float*)d_in[2];
    const float* cost      = (const float*)d_in[3];
    const float* log_scale = (const float*)d_in[4];
    const float* mask      = (const float*)d_in[5];
    const float* Wq0       = (const float*)d_in[6];
    const float* Wq1       = (const float*)d_in[7];
    const float* Wk        = (const float*)d_in[8];
    const float* Wv        = (const float*)d_in[9];
    const float* alpha1    = (const float*)d_in[10];
    const float* alpha2    = (const float*)d_in[11];
    float* out = (float*)d_out;

    const size_t PK_SZ  = (size_t)Bc * 16 * 16384;     //  8,388,608 u16
    const size_t PKW_SZ = (size_t)4 * 8 * 16384;       //    524,288 u16
    const size_t PKB_SZ = (size_t)Bc * 8 * 65536;      // 16,777,216 u16

    // ws layout (u16 units): [PKJ | PKW | PKB | SQ_PK(fp32)]  ~68 MB
    u16* ws   = (u16*)d_ws;
    u16* pkj  = ws;
    u16* pkw  = ws + PK_SZ;
    u16* pkb  = pkw + PKW_SZ;
    float* sq = (float*)(pkb + PKB_SZ);
    (void)ws_size;

    k0w_pk<<<dim3(32, 4), dim3(256), 0, stream>>>(Wk, Wv, Wq0, Wq1, pkw);
    k1_kv<<<dim3(16, 32), dim3(512), 0, stream>>>(jobs, pkw, pkj, pkb);
    k2_q<<<dim3(16, 32), dim3(512), 0, stream>>>(q0, q1, pkw, sq);
    k34<<<512, dim3(512), 0, stream>>>(cost, mask, alpha1, alpha2, log_scale,
                                       pkb, pkj, sq, out);
}

// Round 11
// 252.252 us; speedup vs baseline: 1.0775x; 1.0398x over previous
//
#include <hip/hip_runtime.h>
#include <math.h>

using u16 = unsigned short;
typedef __attribute__((ext_vector_type(8))) short short8;
typedef __attribute__((ext_vector_type(16))) float floatx16;

constexpr int Bc = 32, Nn = 500, Mm = 500, Dd = 256;
constexpr float LOGIT_CLIP = 10.0f;
constexpr float INV_SQRT_D = 1.0f / 16.0f;

__device__ __forceinline__ floatx16 mfma32(short8 a, short8 b, floatx16 c) {
    return __builtin_amdgcn_mfma_f32_32x32x16_bf16(a, b, c, 0, 0, 0);
}

__device__ __forceinline__ floatx16 zero16() {
    floatx16 v = {0.f,0.f,0.f,0.f,0.f,0.f,0.f,0.f,0.f,0.f,0.f,0.f,0.f,0.f,0.f,0.f};
    return v;
}

// split fp32 x into bf16 hi (RTN) + bf16 lo (RTN of residual): x ~= hi + lo
__device__ __forceinline__ void split1(float x, u16& h, u16& l) {
    unsigned u = __float_as_uint(x);
    unsigned rh = (u + 0x7FFFu + ((u >> 16) & 1u)) & 0xFFFF0000u;
    float fh = __uint_as_float(rh);
    float fl = x - fh;
    unsigned ul = __float_as_uint(fl);
    unsigned rl = ul + 0x7FFFu + ((ul >> 16) & 1u);
    h = (u16)(rh >> 16);
    l = (u16)(rl >> 16);
}

__device__ __forceinline__ u16 bf16rtn(float x) {
    unsigned u = __float_as_uint(x);
    return (u16)((u + 0x7FFFu + ((u >> 16) & 1u)) >> 16);
}

__device__ __forceinline__ float fast_tanh(float x) {
    return 1.0f - 2.0f / (__expf(2.0f * x) + 1.0f);
}

__device__ __forceinline__ void split8(const float4& a, const float4& c,
                                       short8& hv, short8& lv) {
    u16 hh, ll;
    split1(a.x, hh, ll); hv[0] = (short)hh; lv[0] = (short)ll;
    split1(a.y, hh, ll); hv[1] = (short)hh; lv[1] = (short)ll;
    split1(a.z, hh, ll); hv[2] = (short)hh; lv[2] = (short)ll;
    split1(a.w, hh, ll); hv[3] = (short)hh; lv[3] = (short)ll;
    split1(c.x, hh, ll); hv[4] = (short)hh; lv[4] = (short)ll;
    split1(c.y, hh, ll); hv[5] = (short)hh; lv[5] = (short)ll;
    split1(c.z, hh, ll); hv[6] = (short)hh; lv[6] = (short)ll;
    split1(c.w, hh, ll); hv[7] = (short)hh; lv[7] = (short)ll;
}

// ===========================================================================
// Packed fragment layouts (u16 units), fragment = [lane(64)][e(8)] = 512 u16:
//   element (row r, col d) lives at lane=((d>>3)&1)<<5 | (r&31), e = d&7.
//   tile stride: 16 dc-chunks x 2 arr(H/L) x 512 = 16384 u16 per 32-row tile.
// PKW [w(4)][dt(8)]  : weights,  w = {Wk,Wv,Wq0,Wq1}, rows = out-dim.
// PKJ [b][mt(16)]    : jobs,   rows m (zero-padded to 512).
// PKB [b][dt(8)][mc(32)][arr(4: ekH,ekL,ekvH,ekvL)][512] : ek/ekv transposed.
// SQ_PK [b][nt(16)][dt(8)][lane(64)][r(16)] fp32 : sigmoid(q), C/D-fragment
//   layout (same (r,lane)->(row,col) map as the MFMA accumulator).
// ===========================================================================

// ---------------------------------------------------------------------------
// K0w_pk: weights fp32 -> packed bf16 hi/lo fragments
// ---------------------------------------------------------------------------
__global__ __launch_bounds__(256) void k0w_pk(const float* __restrict__ s0,
                                              const float* __restrict__ s1,
                                              const float* __restrict__ s2,
                                              const float* __restrict__ s3,
                                              u16* __restrict__ pkw) {
    const float* s = blockIdx.y == 0 ? s0 : blockIdx.y == 1 ? s1 :
                     blockIdx.y == 2 ? s2 : s3;
    const int w = blockIdx.y;
    const int flat = (blockIdx.x * 256 + threadIdx.x) * 8;   // 0..65535
    const int i = flat >> 8, j0 = flat & 255;
    float4 a = *(const float4*)&s[flat];
    float4 c = *(const float4*)&s[flat + 4];
    short8 hv, lv;
    split8(a, c, hv, lv);
    const int dt = i >> 5, i31 = i & 31, dc = j0 >> 4, hp = (j0 >> 3) & 1;
    const size_t off = (size_t)(w * 8 + dt) * 16384 + (size_t)dc * 1024
                     + (size_t)((hp << 5) | i31) * 8;
    *(short8*)&pkw[off] = hv;
    *(short8*)&pkw[off + 512] = lv;
}

// ---------------------------------------------------------------------------
// K12: merged k1 + k2, role = blockIdx.x (FASTEST-varying) so consecutive
// blocks alternate roles -> every CU co-hosts one store-heavy (k1) and one
// load-heavy (k2) block.  Both roles: 33KB LDS, 512 thr -> 4 blocks/CU
// (1024 blocks / 256 CU exactly).
// Role 0 (k1): fused jobs-packing + k/v GEMM -> pkj + PKB, LDS-staged
//   coalesced pkb epilogue (round-10 body verbatim).
// Role 1 (k2): sq = sigmoid(q0@Wq0^T + q1@Wq1^T), TWO-PASS staging
//   (q0 pass then q1 pass reusing one 33KB LDS buffer, same accumulator).
// ---------------------------------------------------------------------------
__global__ __launch_bounds__(512) void k12(const float* __restrict__ jobs,
                                           const float* __restrict__ q0,
                                           const float* __restrict__ q1,
                                           const u16* __restrict__ pkw,
                                           u16* __restrict__ pkj,
                                           u16* __restrict__ pkb,
                                           float* __restrict__ sq) {
    __shared__ u16 tq[2][32][264];   // [H|L][row][col(+pad)]; k1 reuses as epi
    const int t = threadIdx.x;
    const int lane = t & 63, wv = t >> 6;   // wv 0..7
    const int l31 = lane & 31, h = lane >> 5;
    const int tile = blockIdx.y;            // 0..15
    const int b = blockIdx.z;

    if (blockIdx.x == 0) {
        // ================= role 0: k1 (jobs -> pkj, PKB) =================
        const int mt = tile;
        const int M0 = mt * 32;

        // ---- phase A: stage jobs tile (32 rows x 256 cols fp32) ----
#pragma unroll
        for (int it = 0; it < 2; ++it) {
            const int flat = (it * 512 + t) * 8;    // 0..8191
            const int nl = flat >> 8, j0 = flat & 255;
            const int m = M0 + nl;
            short8 hv = {0,0,0,0,0,0,0,0}, lv = {0,0,0,0,0,0,0,0};
            if (m < Mm) {
                const size_t o = ((size_t)b * Mm + m) * Dd + j0;
                float4 a = *(const float4*)&jobs[o];
                float4 c = *(const float4*)&jobs[o + 4];
                split8(a, c, hv, lv);
            }
            *(short8*)&tq[0][nl][j0] = hv;
            *(short8*)&tq[1][nl][j0] = lv;
        }
        __syncthreads();

        // ---- phase B: pkj tile write (fragment layout, coalesced) ----
        {
            u16* dst = pkj + (size_t)(b * 16 + mt) * 16384;
#pragma unroll
            for (int it = 0; it < 4; ++it) {
                const int u = it * 512 + t;        // 0..2047 short8s
                const int dc = u >> 7;
                const int rem = u & 127;
                const int sel = rem >> 6;
                const int idx = rem & 63;
                const int hp = idx >> 5, r31 = idx & 31;
                short8 v = *(const short8*)&tq[sel][r31][dc * 16 + hp * 8];
                *(short8*)&dst[(size_t)dc * 1024 + sel * 512 + (size_t)idx * 8] = v;
            }
        }

        // ---- phase C: GEMM, wave wv -> dt = wv ----
        const int dt = wv;
        const size_t wk  = (size_t)dt * 16384 + (size_t)lane * 8;         // Wk
        const size_t wvb = (size_t)(8 + dt) * 16384 + (size_t)lane * 8;   // Wv

        floatx16 ak = zero16(), av = zero16();

        short8 buf[3][4];
#define K1L(S, DC) { \
        buf[S][0] = *(const short8*)(pkw + wk  + (size_t)(DC) * 1024); \
        buf[S][1] = *(const short8*)(pkw + wk  + (size_t)(DC) * 1024 + 512); \
        buf[S][2] = *(const short8*)(pkw + wvb + (size_t)(DC) * 1024); \
        buf[S][3] = *(const short8*)(pkw + wvb + (size_t)(DC) * 1024 + 512); }

        K1L(0, 0)
        K1L(1, 1)
#pragma unroll
        for (int it = 0; it < 16; ++it) {
            if (it + 2 < 16) { K1L((it + 2) % 3, it + 2) }
            const int c = it % 3;
            const int co = it * 16 + h * 8;
            short8 jH = *(const short8*)&tq[0][l31][co];
            short8 jL = *(const short8*)&tq[1][l31][co];
            ak = mfma32(buf[c][0], jH, ak);
            ak = mfma32(buf[c][0], jL, ak);
            ak = mfma32(buf[c][1], jH, ak);
            av = mfma32(buf[c][2], jH, av);
            av = mfma32(buf[c][2], jL, av);
            av = mfma32(buf[c][3], jH, av);
        }
#undef K1L
        __syncthreads();   // all tq reads complete; reuse LDS as epi buffer

        // ---- phase D: LDS-staged epilogue, two 4-wave halves ----
        u16* epi = &tq[0][0][0];
        const int hp = (l31 >> 3) & 1, ee = l31 & 7, mcl = l31 >> 4;
        const bool v0 = (M0 + l31) < Mm;
#pragma unroll
        for (int half = 0; half < 2; ++half) {
            if ((wv >> 2) == half) {
                const int dtp = wv & 3;
                const int fb = dtp * 4096 + mcl * 2048 + hp * 256 + ee;
#pragma unroll
                for (int r = 0; r < 16; ++r) {
                    const int d31 = (r & 3) + ((r >> 2) << 3) + (h << 2);
                    u16 hh, ll;
                    const float ek = v0 ? __expf(ak[r]) : 0.f;
                    const float ev = v0 ? ek * av[r] : 0.f;
                    split1(ek, hh, ll);
                    epi[fb + d31 * 8] = hh;
                    epi[fb + 512 + d31 * 8] = ll;
                    split1(ev, hh, ll);
                    epi[fb + 1024 + d31 * 8] = hh;
                    epi[fb + 1536 + d31 * 8] = ll;
                }
            }
            __syncthreads();
            // cooperative coalesced store of this half's 16384 u16
#pragma unroll
            for (int it = 0; it < 4; ++it) {
                const int u = it * 512 + t;
                const int dtp = u >> 9;
                const int rem = u & 511;
                const int mc2 = rem >> 8;
                const int rem2 = rem & 255;
                const int arr = rem2 >> 6;
                const int idx = rem2 & 63;
                short8 v = *(const short8*)&epi[dtp * 4096 + mc2 * 2048
                                                + arr * 512 + idx * 8];
                *(short8*)&pkb[((size_t)b * 8 + half * 4 + dtp) * 65536
                               + (size_t)(mt * 2 + mc2) * 2048
                               + (size_t)arr * 512 + (size_t)idx * 8] = v;
            }
            if (half == 0) __syncthreads();
        }
    } else {
        // ================= role 1: k2 (q0,q1 -> sq), two-pass =================
        const int nt = tile;
        const int dt = wv;
        floatx16 acc = zero16();

#pragma unroll
        for (int s = 0; s < 2; ++s) {
            const float* src = s ? q1 : q0;
            if (s) __syncthreads();   // prior pass's LDS reads done before restage
            // ---- stage (32 rows x 256 cols fp32) ----
#pragma unroll
            for (int it = 0; it < 2; ++it) {
                const int flat = (it * 512 + t) * 8;
                const int nl = flat >> 8, j0 = flat & 255;
                const int n = min(nt * 32 + nl, Nn - 1);
                const size_t o = ((size_t)b * Nn + n) * Dd + j0;
                float4 a = *(const float4*)&src[o];
                float4 c = *(const float4*)&src[o + 4];
                short8 hv, lv;
                split8(a, c, hv, lv);
                *(short8*)&tq[0][nl][j0] = hv;
                *(short8*)&tq[1][nl][j0] = lv;
            }
            __syncthreads();

            const size_t wb = (size_t)(16 + s * 8 + dt) * 16384 + (size_t)lane * 8;
            short8 buf[3][2];
#define K2L(S, DC) { \
            buf[S][0] = *(const short8*)(pkw + wb + (size_t)(DC) * 1024); \
            buf[S][1] = *(const short8*)(pkw + wb + (size_t)(DC) * 1024 + 512); }
            K2L(0, 0)
            K2L(1, 1)
#pragma unroll
            for (int it = 0; it < 16; ++it) {
                if (it + 2 < 16) { K2L((it + 2) % 3, it + 2) }
                const int c = it % 3;
                const int co = it * 16 + h * 8;
                short8 aH = *(const short8*)&tq[0][l31][co];
                short8 aL = *(const short8*)&tq[1][l31][co];
                acc = mfma32(aH, buf[c][0], acc);
                acc = mfma32(aH, buf[c][1], acc);
                acc = mfma32(aL, buf[c][0], acc);
            }
#undef K2L
        }

        // ---- epilogue: sq in fragment (C/D) layout, fully coalesced ----
        float* sp = sq + ((((size_t)b * 16 + nt) * 8 + dt) * 64 + lane) * 16;
#pragma unroll
        for (int r = 0; r < 16; ++r) {
            sp[r] = 1.0f / (1.0f + __expf(-acc[r]));
        }
    }
}

// ---------------------------------------------------------------------------
// K34: FUSED AAFM + score + softmax.  Block = (b,nt), 8 waves.
// (round-10 version, unchanged)
// ---------------------------------------------------------------------------
__global__ __launch_bounds__(512) void k34(const float* __restrict__ cost,
                                           const float* __restrict__ mask,
                                           const float* __restrict__ alpha1,
                                           const float* __restrict__ alpha2,
                                           const float* __restrict__ lsc,
                                           const u16* __restrict__ pkb,
                                           const u16* __restrict__ pkj,
                                           const float* __restrict__ sq,
                                           float* __restrict__ out) {
    __shared__ u16 sh[16640];        // phase1-3: tile[32][520]; phase3+: aafm[16][2][512]
    __shared__ float pred[32][8];
    const int i = blockIdx.x;
    const int x = i & 7, j = i >> 3;
    const int nt = j & 15;
    const int b = ((j >> 4) << 3) + x;      // all nt of b on XCD x
    const int t = threadIdx.x;
    const int lane = t & 63, wv = t >> 6;   // wv 0..7
    const int l31 = lane & 31, h = lane >> 5;
    const int N0 = nt << 5;

    // ---- phase 1: expb tile (exp(-a1*ls*cost + mask), bf16, m>=500 zero) ----
    const float a1ls = alpha1[0] * lsc[0];
#pragma unroll
    for (int q = 0; q < 4; ++q) {
        const int flat = (q << 12) + (t << 3);
        const int nl = flat >> 9, m = flat & 511;
        const int n = min(N0 + nl, Nn - 1);
        const size_t o = ((size_t)b * Nn + n) * Mm + m;
        ushort4 w0 = {0, 0, 0, 0}, w1 = {0, 0, 0, 0};
        if (m <= 488) {
            float4 c0 = *(const float4*)&cost[o];
            float4 c1 = *(const float4*)&cost[o + 4];
            float4 k0 = *(const float4*)&mask[o];
            float4 k1 = *(const float4*)&mask[o + 4];
            w0.x = bf16rtn(__expf(fmaf(-a1ls, c0.x, k0.x)));
            w0.y = bf16rtn(__expf(fmaf(-a1ls, c0.y, k0.y)));
            w0.z = bf16rtn(__expf(fmaf(-a1ls, c0.z, k0.z)));
            w0.w = bf16rtn(__expf(fmaf(-a1ls, c0.w, k0.w)));
            w1.x = bf16rtn(__expf(fmaf(-a1ls, c1.x, k1.x)));
            w1.y = bf16rtn(__expf(fmaf(-a1ls, c1.y, k1.y)));
            w1.z = bf16rtn(__expf(fmaf(-a1ls, c1.z, k1.z)));
            w1.w = bf16rtn(__expf(fmaf(-a1ls, c1.w, k1.w)));
        } else if (m == 496) {
            float4 c0 = *(const float4*)&cost[o];
            float4 k0 = *(const float4*)&mask[o];
            w0.x = bf16rtn(__expf(fmaf(-a1ls, c0.x, k0.x)));
            w0.y = bf16rtn(__expf(fmaf(-a1ls, c0.y, k0.y)));
            w0.z = bf16rtn(__expf(fmaf(-a1ls, c0.z, k0.z)));
            w0.w = bf16rtn(__expf(fmaf(-a1ls, c0.w, k0.w)));
        }
        *(ushort4*)&sh[nl * 520 + m] = w0;
        *(ushort4*)&sh[nl * 520 + m + 4] = w1;
    }
    __syncthreads();

    // ---- phase 2: dn/nm accumulation, wave wv -> dt = wv ----
    const size_t bbase = ((size_t)b * 8 + wv) * 65536 + (size_t)lane * 8;
    floatx16 dn = zero16(), nm = zero16();
    short8 buf[3][4];
#define K3L(S, MC) { \
    buf[S][0] = *(const short8*)(pkb + bbase + (size_t)(MC) * 2048); \
    buf[S][1] = *(const short8*)(pkb + bbase + (size_t)(MC) * 2048 + 512); \
    buf[S][2] = *(const short8*)(pkb + bbase + (size_t)(MC) * 2048 + 1024); \
    buf[S][3] = *(const short8*)(pkb + bbase + (size_t)(MC) * 2048 + 1536); }

    K3L(0, 0)
    K3L(1, 1)
#pragma unroll
    for (int mc = 0; mc < 32; ++mc) {
        if (mc + 2 < 32) { K3L((mc + 2) % 3, mc + 2) }
        const int c = mc % 3;
        short8 aa = *(const short8*)&sh[l31 * 520 + mc * 16 + h * 8];
        dn = mfma32(aa, buf[c][0], dn);
        dn = mfma32(aa, buf[c][1], dn);
        nm = mfma32(aa, buf[c][2], nm);
        nm = mfma32(aa, buf[c][3], nm);
    }
#undef K3L
    __syncthreads();   // all tile reads done; safe to overwrite with aafm

    // ---- phase 3: aafm -> bf16 H/L A-fragments in LDS ----
    {
        const float* sp = sq + ((((size_t)b * 16 + nt) * 8 + wv) * 64 + lane) * 16;
        const int hp = (l31 >> 3) & 1, ee = l31 & 7;
        const int fo = (wv * 2 + (l31 >> 4)) * 1024 + hp * 256 + ee;
#pragma unroll
        for (int r = 0; r < 16; ++r) {
            const int n31 = (r & 3) + ((r >> 2) << 3) + (h << 2);
            const float d0 = dn[r];
            const float w0 = (d0 != 0.f) ? nm[r] / d0 : 0.f;
            u16 hh, ll;
            split1(sp[r] * w0, hh, ll);
            sh[fo + n31 * 8] = hh;
            sh[fo + 512 + n31 * 8] = ll;
        }
    }
    __syncthreads();

    // ---- phase 4: score GEMM; wave wv -> m block [wv*64, wv*64+64) ----
    const u16* jb0p = pkj + ((size_t)b * 16 + wv * 2) * 16384 + (size_t)lane * 8;
    const u16* jb1p = jb0p + 16384;
    const int m0g = wv * 64 + l31;
    const int m1g = m0g + 32;

    floatx16 acc0 = zero16(), acc1 = zero16();
    short8 jbuf[3][4];
#define K4L(S, DC) { \
    jbuf[S][0] = *(const short8*)(jb0p + (size_t)(DC) * 1024); \
    jbuf[S][1] = *(const short8*)(jb0p + (size_t)(DC) * 1024 + 512); \
    jbuf[S][2] = *(const short8*)(jb1p + (size_t)(DC) * 1024); \
    jbuf[S][3] = *(const short8*)(jb1p + (size_t)(DC) * 1024 + 512); }

    K4L(0, 0)
    K4L(1, 1)
#pragma unroll
    for (int dc = 0; dc < 16; ++dc) {
        if (dc + 2 < 16) { K4L((dc + 2) % 3, dc + 2) }
        const int c = dc % 3;
        short8 aH = *(const short8*)&sh[dc * 1024 + lane * 8];
        short8 aL = *(const short8*)&sh[dc * 1024 + 512 + lane * 8];
        acc0 = mfma32(aH, jbuf[c][0], acc0);
        acc0 = mfma32(aH, jbuf[c][1], acc0);
        acc0 = mfma32(aL, jbuf[c][0], acc0);
        acc1 = mfma32(aH, jbuf[c][2], acc1);
        acc1 = mfma32(aH, jbuf[c][3], acc1);
        acc1 = mfma32(aL, jbuf[c][2], acc1);
    }
#undef K4L

    // ---- phase 5: logits ----
    float lg0[16], lg1[16];
    const float a2ls = alpha2[0] * lsc[0];
    const size_t cb = (size_t)b * Nn * Mm;
#pragma unroll
    for (int r = 0; r < 16; ++r) {
        const int row = (r & 3) + ((r >> 2) << 3) + (h << 2);
        const int n = N0 + row;
        if (n < Nn) {
            const size_t o = cb + (size_t)n * Mm + m0g;
            lg0[r] = LOGIT_CLIP * fast_tanh(fmaf(-a2ls, cost[o], acc0[r] * INV_SQRT_D)) + mask[o];
            if (m1g < Mm) {
                const size_t o1 = o + 32;
                lg1[r] = LOGIT_CLIP * fast_tanh(fmaf(-a2ls, cost[o1], acc1[r] * INV_SQRT_D)) + mask[o1];
            } else lg1[r] = -1e30f;
        } else { lg0[r] = -1e30f; lg1[r] = -1e30f; }
    }

    // ---- row max: butterfly within 32-lane half, then cross-wave via LDS ----
    float rm[16];
#pragma unroll
    for (int r = 0; r < 16; ++r) rm[r] = fmaxf(lg0[r], lg1[r]);
#pragma unroll
    for (int d = 1; d < 32; d <<= 1)
#pragma unroll
        for (int r = 0; r < 16; ++r) rm[r] = fmaxf(rm[r], __shfl_xor(rm[r], d));
    if (l31 == 0) {
#pragma unroll
        for (int r = 0; r < 16; ++r)
            pred[(r & 3) + ((r >> 2) << 3) + (h << 2)][wv] = rm[r];
    }
    __syncthreads();
    float fm[16];
#pragma unroll
    for (int r = 0; r < 16; ++r) {
        const int row = (r & 3) + ((r >> 2) << 3) + (h << 2);
        float v = pred[row][0];
#pragma unroll
        for (int w = 1; w < 8; ++w) v = fmaxf(v, pred[row][w]);
        fm[r] = v;
    }
    __syncthreads();

    // ---- exp + row sum ----
    float sm[16];
#pragma unroll
    for (int r = 0; r < 16; ++r) {
        lg0[r] = __expf(lg0[r] - fm[r]);
        lg1[r] = __expf(lg1[r] - fm[r]);
        sm[r] = lg0[r] + lg1[r];
    }
#pragma unroll
    for (int d = 1; d < 32; d <<= 1)
#pragma unroll
        for (int r = 0; r < 16; ++r) sm[r] += __shfl_xor(sm[r], d);
    if (l31 == 0) {
#pragma unroll
        for (int r = 0; r < 16; ++r)
            pred[(r & 3) + ((r >> 2) << 3) + (h << 2)][wv] = sm[r];
    }
    __syncthreads();

    // ---- normalize + store ----
#pragma unroll
    for (int r = 0; r < 16; ++r) {
        const int row = (r & 3) + ((r >> 2) << 3) + (h << 2);
        const int n = N0 + row;
        if (n < Nn) {
            float s = pred[row][0];
#pragma unroll
            for (int w = 1; w < 8; ++w) s += pred[row][w];
            const float inv = 1.0f / s;
            const size_t o = cb + (size_t)n * Mm + m0g;
            out[o] = lg0[r] * inv;
            if (m1g < Mm) out[o + 32] = lg1[r] * inv;
        }
    }
}

// ---------------------------------------------------------------------------
extern "C" void kernel_launch(void* const* d_in, const int* in_sizes, int n_in,
                              void* d_out, int out_size, void* d_ws, size_t ws_size,
                              hipStream_t stream) {
    const float* q0        = (const float*)d_in[0];
    const float* jobs      = (const float*)d_in[1];
    const float* q1        = (const float*)d_in[2];
    const float* cost      = (const float*)d_in[3];
    const float* log_scale = (const float*)d_in[4];
    const float* mask      = (const float*)d_in[5];
    const float* Wq0       = (const float*)d_in[6];
    const float* Wq1       = (const float*)d_in[7];
    const float* Wk        = (const float*)d_in[8];
    const float* Wv        = (const float*)d_in[9];
    const float* alpha1    = (const float*)d_in[10];
    const float* alpha2    = (const float*)d_in[11];
    float* out = (float*)d_out;

    const size_t PK_SZ  = (size_t)Bc * 16 * 16384;     //  8,388,608 u16
    const size_t PKW_SZ = (size_t)4 * 8 * 16384;       //    524,288 u16
    const size_t PKB_SZ = (size_t)Bc * 8 * 65536;      // 16,777,216 u16

    // ws layout (u16 units): [PKJ | PKW | PKB | SQ_PK(fp32)]  ~68 MB
    u16* ws   = (u16*)d_ws;
    u16* pkj  = ws;
    u16* pkw  = ws + PK_SZ;
    u16* pkb  = pkw + PKW_SZ;
    float* sq = (float*)(pkb + PKB_SZ);
    (void)ws_size;

    k0w_pk<<<dim3(32, 4), dim3(256), 0, stream>>>(Wk, Wv, Wq0, Wq1, pkw);
    k12<<<dim3(2, 16, 32), dim3(512), 0, stream>>>(jobs, q0, q1, pkw, pkj, pkb, sq);
    k34<<<512, dim3(512), 0, stream>>>(cost, mask, alpha1, alpha2, log_scale,
                                       pkb, pkj, sq, out);
}